// Round 2
// baseline (811.714 us; speedup 1.0000x reference)
//
#include <hip/hip_runtime.h>

#define N_TOK 16384
#define HIDN  768
#define MIDN  5376
#define COMBN 3840
#define NH    12
#define DHD   64
#define CHUNK 256
#define WIN   256

typedef short s16x8 __attribute__((ext_vector_type(8)));
typedef short s16x4 __attribute__((ext_vector_type(4)));
typedef float f32x4 __attribute__((ext_vector_type(4)));

__device__ __forceinline__ float bf2f(unsigned short u){
  union { unsigned u; float f; } x; x.u = ((unsigned)u) << 16; return x.f;
}
__device__ __forceinline__ unsigned short f2bf(float f){
  union { float f; unsigned u; } x; x.f = f;
  unsigned r = x.u + 0x7fffu + ((x.u >> 16) & 1u);
  return (unsigned short)(r >> 16);
}
__device__ __forceinline__ float gelu_tanh(float x){
  float u = 0.7978845608028654f * (x + 0.044715f * x * x * x);
  u = fminf(fmaxf(u, -30.f), 30.f);
  float e = __expf(2.f * u);
  return 0.5f * x * (1.f + (e - 1.f) / (e + 1.f));
}
__device__ __forceinline__ void glds16(const void* g, void* l){
  __builtin_amdgcn_global_load_lds(
      (const __attribute__((address_space(1))) unsigned*)g,
      (__attribute__((address_space(3))) unsigned*)l, 16, 0, 0);
}

// ------- transpose + downcast: in fp32 [R][Cc] -> out bf16 [Cc][R] -------
__global__ __launch_bounds__(256) void transpose_f2b(
    const float* __restrict__ in, unsigned short* __restrict__ out,
    int R, int Cc)
{
  __shared__ short t[64 * 72];
  const int tid = threadIdx.x;
  const int r0 = blockIdx.y * 64, c0 = blockIdx.x * 64;
  #pragma unroll
  for (int rep = 0; rep < 4; rep++){
    int v = tid + 256 * rep;
    int r = v >> 4, s = v & 15;
    float4 d = *(const float4*)(in + (size_t)(r0 + r) * Cc + c0 + s * 4);
    s16x4 o = { (short)f2bf(d.x), (short)f2bf(d.y), (short)f2bf(d.z), (short)f2bf(d.w) };
    *(s16x4*)(t + r * 72 + s * 4) = o;
  }
  __syncthreads();
  #pragma unroll
  for (int rep = 0; rep < 2; rep++){
    int v = tid + 256 * rep;
    int c = v & 63, s2 = v >> 6;
    s16x8 d;
    #pragma unroll
    for (int j = 0; j < 8; j++) d[j] = t[(s2 * 8 + j) * 72 + c];
    *(s16x8*)(out + (size_t)(c0 + c) * R + r0 + s2 * 8) = d;
  }
}

// ------- layernorm: fp32 in -> bf16 out, one wave per row -------
__global__ __launch_bounds__(256) void ln_kernel(
    const float* __restrict__ x, const float* __restrict__ sc,
    const float* __restrict__ ofs, unsigned short* __restrict__ xn)
{
  const int lane = threadIdx.x & 63, wv = threadIdx.x >> 6;
  const int row = blockIdx.x * 4 + wv;
  const float4* xr = (const float4*)(x + (size_t)row * HIDN);
  float4 vals[3];
  float sum = 0.f, sq = 0.f;
  #pragma unroll
  for (int j = 0; j < 3; j++){
    vals[j] = xr[lane + 64 * j];
    sum += vals[j].x + vals[j].y + vals[j].z + vals[j].w;
    sq  += vals[j].x * vals[j].x + vals[j].y * vals[j].y
         + vals[j].z * vals[j].z + vals[j].w * vals[j].w;
  }
  #pragma unroll
  for (int o = 1; o < 64; o <<= 1){ sum += __shfl_xor(sum, o); sq += __shfl_xor(sq, o); }
  const float mu = sum * (1.f / HIDN);
  const float rs = rsqrtf(fmaxf(sq * (1.f / HIDN) - mu * mu, 0.f) + 1e-5f);
  s16x4* xo = (s16x4*)(xn + (size_t)row * HIDN);
  const float4* scp = (const float4*)sc;
  const float4* ofp = (const float4*)ofs;
  #pragma unroll
  for (int j = 0; j < 3; j++){
    int p = lane + 64 * j;
    float4 s = scp[p], o = ofp[p];
    s16x4 w;
    w[0] = (short)f2bf((vals[j].x - mu) * rs * s.x + o.x);
    w[1] = (short)f2bf((vals[j].y - mu) * rs * s.y + o.y);
    w[2] = (short)f2bf((vals[j].z - mu) * rs * s.z + o.z);
    w[3] = (short)f2bf((vals[j].w - mu) * rs * s.w + o.w);
    xo[p] = w;
  }
}

// ------- GEMM C = A[M][K] * BT[N][K]^T (bf16), 128x128 tile, BK=32 -------
// mode 0: +b_in; split q/k/v head-major bf16, gelu(ff)->comb cols 768..
// mode 1: +b_out + bf16 xn residual -> fp32 out
__global__ __launch_bounds__(256) void gemm_bt(
    const unsigned short* __restrict__ A, const unsigned short* __restrict__ BT,
    const float* __restrict__ bias, int K, int mode,
    unsigned short* __restrict__ qb, unsigned short* __restrict__ kb,
    unsigned short* __restrict__ vb, unsigned short* __restrict__ comb,
    const unsigned short* __restrict__ xn, float* __restrict__ outp)
{
  __shared__ short As[128 * 32];
  __shared__ short Bs[128 * 32];
  const int tid = threadIdx.x, lane = tid & 63, wv = tid >> 6;
  const int quad = lane >> 4, l15 = lane & 15;
  const int m0 = blockIdx.y * 128, n0 = blockIdx.x * 128;
  const int wr = (wv >> 1) * 64, wc = (wv & 1) * 64;

  f32x4 acc[4][4];
  #pragma unroll
  for (int i = 0; i < 4; i++)
    #pragma unroll
    for (int j = 0; j < 4; j++) acc[i][j] = (f32x4){0.f,0.f,0.f,0.f};

  const int srow = tid >> 2, sseg = tid & 3;
  const unsigned short* Ap = A  + (size_t)(m0 + srow) * K + sseg * 8;
  const unsigned short* Bp = BT + (size_t)(n0 + srow) * K + sseg * 8;
  const size_t rstep = (size_t)64 * K;
  char* AsB = ((char*)As) + tid * 16;
  char* BsB = ((char*)Bs) + tid * 16;

  for (int kt = 0; kt < K; kt += 32){
    __syncthreads();
    glds16(Ap + kt,         AsB);
    glds16(Ap + kt + rstep, AsB + 4096);
    glds16(Bp + kt,         BsB);
    glds16(Bp + kt + rstep, BsB + 4096);
    __syncthreads();
    s16x8 a[4], b[4];
    #pragma unroll
    for (int rt = 0; rt < 4; rt++) a[rt] = *(const s16x8*)(As + (wr + rt*16 + l15)*32 + quad*8);
    #pragma unroll
    for (int ct = 0; ct < 4; ct++) b[ct] = *(const s16x8*)(Bs + (wc + ct*16 + l15)*32 + quad*8);
    #pragma unroll
    for (int rt = 0; rt < 4; rt++)
      #pragma unroll
      for (int ct = 0; ct < 4; ct++)
        acc[rt][ct] = __builtin_amdgcn_mfma_f32_16x16x32_bf16(a[rt], b[ct], acc[rt][ct], 0, 0, 0);
  }

  #pragma unroll
  for (int rt = 0; rt < 4; rt++){
    #pragma unroll
    for (int ct = 0; ct < 4; ct++){
      const int col = n0 + wc + ct * 16 + l15;
      const float bsv = bias[col];
      #pragma unroll
      for (int r = 0; r < 4; r++){
        const int row = m0 + wr + rt * 16 + quad * 4 + r;   // C layout: row=quad*4+reg
        float val = acc[rt][ct][r] + bsv;
        if (mode == 0){
          if (col < 2304){
            unsigned short* dst; int cc;
            if (col < 768)      { dst = qb; cc = col; }
            else if (col < 1536){ dst = kb; cc = col - 768; }
            else                { dst = vb; cc = col - 1536; }
            dst[((size_t)(cc >> 6) * N_TOK + row) * DHD + (cc & 63)] = f2bf(val);
          } else {
            comb[(size_t)row * COMBN + (col - 1536)] = f2bf(gelu_tanh(val));
          }
        } else {
          const size_t o = (size_t)row * HIDN + col;
          outp[o] = bf2f(xn[o]) + val;
        }
      }
    }
  }
}

// ------- fused RoPE + chunked local attention -------
__global__ __launch_bounds__(256) void attn_kernel(
    const unsigned short* __restrict__ qb, const unsigned short* __restrict__ kb,
    const unsigned short* __restrict__ vb, const float* __restrict__ psin,
    const float* __restrict__ pcos, unsigned short* __restrict__ comb,
    const int* __restrict__ lenp)
{
  __shared__ short Ks[32 * 64];      // [key][dh]
  __shared__ short Vt[64 * 32];      // [dh][key]
  __shared__ short Ps[4][64 * 40];   // per-wave P scratch
  const int tid = threadIdx.x, lane = tid & 63, wv = tid >> 6;
  const int quad = lane >> 4, l15 = lane & 15;
  const int h = blockIdx.y, c = blockIdx.x;
  const unsigned lm = ~((unsigned)lenp[0] - 1u);
  const int i0 = c * CHUNK + wv * 64;
  const unsigned short* qh = qb + (size_t)h * N_TOK * DHD;
  const unsigned short* kh = kb + (size_t)h * N_TOK * DHD;
  const unsigned short* vh = vb + (size_t)h * N_TOK * DHD;

  // Q fragments: RoPE + 1/8 scale, A-layout [m=lane&15][k=quad*8+j]
  s16x8 qf[4][2];
  #pragma unroll
  for (int rt = 0; rt < 4; rt++){
    const int tok = i0 + rt * 16 + l15;
    const unsigned short* qr = qh + (size_t)tok * DHD;
    #pragma unroll
    for (int ks = 0; ks < 2; ks++){
      const int base = ks * 32 + quad * 8;
      s16x8 qv = *(const s16x8*)(qr + base);
      const float* sr = psin + (size_t)tok * DHD + base;
      const float* cr = pcos + (size_t)tok * DHD + base;
      float4 sA = *(const float4*)sr, sB = *(const float4*)(sr + 4);
      float4 cA = *(const float4*)cr, cB = *(const float4*)(cr + 4);
      float sv[4] = {sA.x, sA.z, sB.x, sB.z};
      float cv[4] = {cA.x, cA.z, cB.x, cB.z};
      s16x8 o;
      #pragma unroll
      for (int p = 0; p < 4; p++){
        float e = bf2f((unsigned short)qv[2*p]);
        float d = bf2f((unsigned short)qv[2*p+1]);
        o[2*p]   = (short)f2bf((e * cv[p] - d * sv[p]) * 0.125f);
        o[2*p+1] = (short)f2bf((d * cv[p] + e * sv[p]) * 0.125f);
      }
      qf[rt][ks] = o;
    }
  }

  f32x4 O[4][4];
  float mm[4][4], ll[4][4];
  #pragma unroll
  for (int rt = 0; rt < 4; rt++)
    #pragma unroll
    for (int j = 0; j < 4; j++){ O[rt][j] = (f32x4){0,0,0,0}; mm[rt][j] = -1e30f; ll[rt][j] = 0.f; }
  short* myP = &Ps[wv][0];

  for (int t = 0; t < 16; t++){
    const int jb = c * CHUNK - 256 + t * 32;
    __syncthreads();
    { // stage K (with RoPE) and V^T
      const int r = tid >> 3, s = tid & 7;
      const int tok = jb + r;
      s16x8 ko = {0,0,0,0,0,0,0,0};
      s16x8 vo = {0,0,0,0,0,0,0,0};
      if (tok >= 0){
        s16x8 kv = *(const s16x8*)(kh + (size_t)tok * DHD + s * 8);
        vo       = *(const s16x8*)(vh + (size_t)tok * DHD + s * 8);
        const float* sr = psin + (size_t)tok * DHD + s * 8;
        const float* cr = pcos + (size_t)tok * DHD + s * 8;
        float4 sA = *(const float4*)sr, sB = *(const float4*)(sr + 4);
        float4 cA = *(const float4*)cr, cB = *(const float4*)(cr + 4);
        float sv[4] = {sA.x, sA.z, sB.x, sB.z};
        float cv[4] = {cA.x, cA.z, cB.x, cB.z};
        #pragma unroll
        for (int p = 0; p < 4; p++){
          float e = bf2f((unsigned short)kv[2*p]);
          float d = bf2f((unsigned short)kv[2*p+1]);
          ko[2*p]   = (short)f2bf(e * cv[p] - d * sv[p]);
          ko[2*p+1] = (short)f2bf(d * cv[p] + e * sv[p]);
        }
      }
      *(s16x8*)(Ks + r * 64 + s * 8) = ko;
      #pragma unroll
      for (int j = 0; j < 8; j++) Vt[(s * 8 + j) * 32 + r] = vo[j];
    }
    __syncthreads();

    bool skip = (jb > i0 + 63) || (jb + 31 < i0 - 255) || (jb + 31 < 0);
    if (!skip && jb >= 0){
      unsigned q0 = (unsigned)i0 & lm;
      unsigned k0 = (unsigned)jb & lm;
      if (q0 != k0) skip = true;   // tiles never straddle a 512-aligned segment
    }
    if (skip) continue;

    #pragma unroll
    for (int rt = 0; rt < 4; rt++){
      f32x4 sc[2];
      #pragma unroll
      for (int ct = 0; ct < 2; ct++){
        const s16x8 b0 = *(const s16x8*)(Ks + (ct*16 + l15)*64 + quad*8);
        const s16x8 b1 = *(const s16x8*)(Ks + (ct*16 + l15)*64 + 32 + quad*8);
        f32x4 a = (f32x4){0,0,0,0};
        a = __builtin_amdgcn_mfma_f32_16x16x32_bf16(qf[rt][0], b0, a, 0, 0, 0);
        a = __builtin_amdgcn_mfma_f32_16x16x32_bf16(qf[rt][1], b1, a, 0, 0, 0);
        sc[ct] = a;
      }
      float alph[4];
      #pragma unroll
      for (int r = 0; r < 4; r++){
        const int i = i0 + rt*16 + quad*4 + r;
        #pragma unroll
        for (int ct = 0; ct < 2; ct++){
          const int j = jb + ct*16 + l15;
          const bool act = (j >= 0) && (i >= j) && (i - j < WIN);
          if (!act) sc[ct][r] = -1e30f;
        }
        float mx = fmaxf(sc[0][r], sc[1][r]);
        mx = fmaxf(mx, __shfl_xor(mx, 1));
        mx = fmaxf(mx, __shfl_xor(mx, 2));
        mx = fmaxf(mx, __shfl_xor(mx, 4));
        mx = fmaxf(mx, __shfl_xor(mx, 8));
        const float mnew = fmaxf(mm[rt][r], mx);
        const float al = __expf(mm[rt][r] - mnew);
        mm[rt][r] = mnew;
        float p0 = __expf(sc[0][r] - mnew);
        float p1 = __expf(sc[1][r] - mnew);
        sc[0][r] = p0; sc[1][r] = p1;
        float rsum = p0 + p1;
        rsum += __shfl_xor(rsum, 1);
        rsum += __shfl_xor(rsum, 2);
        rsum += __shfl_xor(rsum, 4);
        rsum += __shfl_xor(rsum, 8);
        ll[rt][r] = ll[rt][r] * al + rsum;
        alph[r] = al;
      }
      #pragma unroll
      for (int co = 0; co < 4; co++)
        #pragma unroll
        for (int r = 0; r < 4; r++) O[rt][co][r] *= alph[r];
      #pragma unroll
      for (int r = 0; r < 4; r++){
        const int prow = rt*16 + quad*4 + r;
        myP[prow*40 + l15]      = (short)f2bf(sc[0][r]);
        myP[prow*40 + 16 + l15] = (short)f2bf(sc[1][r]);
      }
      const s16x8 pf = *(const s16x8*)(myP + (rt*16 + l15)*40 + quad*8);
      #pragma unroll
      for (int co = 0; co < 4; co++){
        const s16x8 vf = *(const s16x8*)(Vt + (co*16 + l15)*32 + quad*8);
        O[rt][co] = __builtin_amdgcn_mfma_f32_16x16x32_bf16(pf, vf, O[rt][co], 0, 0, 0);
      }
    }
  }

  #pragma unroll
  for (int rt = 0; rt < 4; rt++)
    #pragma unroll
    for (int co = 0; co < 4; co++)
      #pragma unroll
      for (int r = 0; r < 4; r++){
        const int tok = i0 + rt*16 + quad*4 + r;
        comb[(size_t)tok * COMBN + h*DHD + co*16 + l15] = f2bf(O[rt][co][r] / ll[rt][r]);
      }
}

extern "C" void kernel_launch(void* const* d_in, const int* in_sizes, int n_in,
                              void* d_out, int out_size, void* d_ws, size_t ws_size,
                              hipStream_t stream)
{
  const float* x     = (const float*)d_in[0];
  // d_in[1] = normed_ages (unused by reference)
  const float* psin  = (const float*)d_in[2];
  const float* pcos  = (const float*)d_in[3];
  const float* lns   = (const float*)d_in[4];
  const float* lno   = (const float*)d_in[5];
  const float* w_in  = (const float*)d_in[6];
  const float* b_in  = (const float*)d_in[7];
  const float* w_out = (const float*)d_in[8];
  const float* b_out = (const float*)d_in[9];
  const int*   lenp  = (const int*)d_in[10];
  float* out = (float*)d_out;

  char* ws = (char*)d_ws;
  size_t off = 0;
  unsigned short* xn    = (unsigned short*)(ws + off); off += (size_t)N_TOK * HIDN * 2;
  unsigned short* wInT  = (unsigned short*)(ws + off); off += (size_t)MIDN * HIDN * 2;
  unsigned short* wOutT = (unsigned short*)(ws + off); off += (size_t)HIDN * COMBN * 2;
  unsigned short* qbuf  = (unsigned short*)(ws + off); off += (size_t)NH * N_TOK * DHD * 2;
  unsigned short* kbuf  = (unsigned short*)(ws + off); off += (size_t)NH * N_TOK * DHD * 2;
  unsigned short* vbuf  = (unsigned short*)(ws + off); off += (size_t)NH * N_TOK * DHD * 2;
  unsigned short* comb  = (unsigned short*)(ws + off); off += (size_t)N_TOK * COMBN * 2;

  transpose_f2b<<<dim3(MIDN/64, HIDN/64), 256, 0, stream>>>(w_in, wInT, HIDN, MIDN);
  transpose_f2b<<<dim3(HIDN/64, COMBN/64), 256, 0, stream>>>(w_out, wOutT, COMBN, HIDN);
  ln_kernel<<<dim3(N_TOK/4), 256, 0, stream>>>(x, lns, lno, xn);
  gemm_bt<<<dim3(MIDN/128, N_TOK/128), 256, 0, stream>>>(
      xn, wInT, b_in, HIDN, 0, qbuf, kbuf, vbuf, comb, nullptr, nullptr);
  attn_kernel<<<dim3(N_TOK/CHUNK, NH), 256, 0, stream>>>(
      qbuf, kbuf, vbuf, psin, pcos, comb, lenp);
  gemm_bt<<<dim3(HIDN/128, N_TOK/128), 256, 0, stream>>>(
      comb, wOutT, b_out, COMBN, 1, nullptr, nullptr, nullptr, nullptr, xn, out);
}

// Round 3
// 723.735 us; speedup vs baseline: 1.1216x; 1.1216x over previous
//
#include <hip/hip_runtime.h>

#define N_TOK 16384
#define HIDN  768
#define MIDN  5376
#define COMBN 3840
#define NH    12
#define DHD   64
#define CHUNK 256
#define WIN   256

typedef short s16x8 __attribute__((ext_vector_type(8)));
typedef short s16x4 __attribute__((ext_vector_type(4)));
typedef float f32x4 __attribute__((ext_vector_type(4)));

__device__ __forceinline__ float bf2f(unsigned short u){
  union { unsigned u; float f; } x; x.u = ((unsigned)u) << 16; return x.f;
}
__device__ __forceinline__ unsigned short f2bf(float f){
  union { float f; unsigned u; } x; x.f = f;
  unsigned r = x.u + 0x7fffu + ((x.u >> 16) & 1u);
  return (unsigned short)(r >> 16);
}
__device__ __forceinline__ float gelu_tanh(float x){
  float u = 0.7978845608028654f * (x + 0.044715f * x * x * x);
  u = fminf(fmaxf(u, -30.f), 30.f);
  float e = __expf(2.f * u);
  return 0.5f * x * (1.f + (e - 1.f) / (e + 1.f));
}
__device__ __forceinline__ void glds16(const void* g, void* l){
  __builtin_amdgcn_global_load_lds(
      (const __attribute__((address_space(1))) unsigned*)g,
      (__attribute__((address_space(3))) unsigned*)l, 16, 0, 0);
}

// ------- transpose + downcast: in fp32 [R][Cc] -> out bf16 [Cc][R] -------
__global__ __launch_bounds__(256) void transpose_f2b(
    const float* __restrict__ in, unsigned short* __restrict__ out,
    int R, int Cc)
{
  __shared__ short t[64 * 72];
  const int tid = threadIdx.x;
  const int r0 = blockIdx.y * 64, c0 = blockIdx.x * 64;
  #pragma unroll
  for (int rep = 0; rep < 4; rep++){
    int v = tid + 256 * rep;
    int r = v >> 4, s = v & 15;
    float4 d = *(const float4*)(in + (size_t)(r0 + r) * Cc + c0 + s * 4);
    s16x4 o = { (short)f2bf(d.x), (short)f2bf(d.y), (short)f2bf(d.z), (short)f2bf(d.w) };
    *(s16x4*)(t + r * 72 + s * 4) = o;
  }
  __syncthreads();
  #pragma unroll
  for (int rep = 0; rep < 2; rep++){
    int v = tid + 256 * rep;
    int c = v & 63, s2 = v >> 6;
    s16x8 d;
    #pragma unroll
    for (int j = 0; j < 8; j++) d[j] = t[(s2 * 8 + j) * 72 + c];
    *(s16x8*)(out + (size_t)(c0 + c) * R + r0 + s2 * 8) = d;
  }
}

// ------- layernorm: fp32 in -> bf16 out, one wave per row -------
__global__ __launch_bounds__(256) void ln_kernel(
    const float* __restrict__ x, const float* __restrict__ sc,
    const float* __restrict__ ofs, unsigned short* __restrict__ xn)
{
  const int lane = threadIdx.x & 63, wv = threadIdx.x >> 6;
  const int row = blockIdx.x * 4 + wv;
  const float4* xr = (const float4*)(x + (size_t)row * HIDN);
  float4 vals[3];
  float sum = 0.f, sq = 0.f;
  #pragma unroll
  for (int j = 0; j < 3; j++){
    vals[j] = xr[lane + 64 * j];
    sum += vals[j].x + vals[j].y + vals[j].z + vals[j].w;
    sq  += vals[j].x * vals[j].x + vals[j].y * vals[j].y
         + vals[j].z * vals[j].z + vals[j].w * vals[j].w;
  }
  #pragma unroll
  for (int o = 1; o < 64; o <<= 1){ sum += __shfl_xor(sum, o); sq += __shfl_xor(sq, o); }
  const float mu = sum * (1.f / HIDN);
  const float rs = rsqrtf(fmaxf(sq * (1.f / HIDN) - mu * mu, 0.f) + 1e-5f);
  s16x4* xo = (s16x4*)(xn + (size_t)row * HIDN);
  const float4* scp = (const float4*)sc;
  const float4* ofp = (const float4*)ofs;
  #pragma unroll
  for (int j = 0; j < 3; j++){
    int p = lane + 64 * j;
    float4 s = scp[p], o = ofp[p];
    s16x4 w;
    w[0] = (short)f2bf((vals[j].x - mu) * rs * s.x + o.x);
    w[1] = (short)f2bf((vals[j].y - mu) * rs * s.y + o.y);
    w[2] = (short)f2bf((vals[j].z - mu) * rs * s.z + o.z);
    w[3] = (short)f2bf((vals[j].w - mu) * rs * s.w + o.w);
    xo[p] = w;
  }
}

// ------- GEMM C = A[M][K] * BT[N][K]^T (bf16), 128x128 tile, BK=32 -------
__global__ __launch_bounds__(256) void gemm_bt(
    const unsigned short* __restrict__ A, const unsigned short* __restrict__ BT,
    const float* __restrict__ bias, int K, int mode,
    unsigned short* __restrict__ qb, unsigned short* __restrict__ kb,
    unsigned short* __restrict__ vb, unsigned short* __restrict__ comb,
    const unsigned short* __restrict__ xn, float* __restrict__ outp)
{
  __shared__ short As[128 * 32];
  __shared__ short Bs[128 * 32];
  const int tid = threadIdx.x, lane = tid & 63, wv = tid >> 6;
  const int quad = lane >> 4, l15 = lane & 15;
  const int m0 = blockIdx.y * 128, n0 = blockIdx.x * 128;
  const int wr = (wv >> 1) * 64, wc = (wv & 1) * 64;

  f32x4 acc[4][4];
  #pragma unroll
  for (int i = 0; i < 4; i++)
    #pragma unroll
    for (int j = 0; j < 4; j++) acc[i][j] = (f32x4){0.f,0.f,0.f,0.f};

  const int srow = tid >> 2, sseg = tid & 3;
  const unsigned short* Ap = A  + (size_t)(m0 + srow) * K + sseg * 8;
  const unsigned short* Bp = BT + (size_t)(n0 + srow) * K + sseg * 8;
  const size_t rstep = (size_t)64 * K;
  char* AsB = ((char*)As) + tid * 16;
  char* BsB = ((char*)Bs) + tid * 16;

  for (int kt = 0; kt < K; kt += 32){
    __syncthreads();
    glds16(Ap + kt,         AsB);
    glds16(Ap + kt + rstep, AsB + 4096);
    glds16(Bp + kt,         BsB);
    glds16(Bp + kt + rstep, BsB + 4096);
    __syncthreads();
    s16x8 a[4], b[4];
    #pragma unroll
    for (int rt = 0; rt < 4; rt++) a[rt] = *(const s16x8*)(As + (wr + rt*16 + l15)*32 + quad*8);
    #pragma unroll
    for (int ct = 0; ct < 4; ct++) b[ct] = *(const s16x8*)(Bs + (wc + ct*16 + l15)*32 + quad*8);
    #pragma unroll
    for (int rt = 0; rt < 4; rt++)
      #pragma unroll
      for (int ct = 0; ct < 4; ct++)
        acc[rt][ct] = __builtin_amdgcn_mfma_f32_16x16x32_bf16(a[rt], b[ct], acc[rt][ct], 0, 0, 0);
  }

  #pragma unroll
  for (int rt = 0; rt < 4; rt++){
    #pragma unroll
    for (int ct = 0; ct < 4; ct++){
      const int col = n0 + wc + ct * 16 + l15;
      const float bsv = bias[col];
      #pragma unroll
      for (int r = 0; r < 4; r++){
        const int row = m0 + wr + rt * 16 + quad * 4 + r;
        float val = acc[rt][ct][r] + bsv;
        if (mode == 0){
          if (col < 2304){
            unsigned short* dst; int cc;
            if (col < 768)      { dst = qb; cc = col; }
            else if (col < 1536){ dst = kb; cc = col - 768; }
            else                { dst = vb; cc = col - 1536; }
            dst[((size_t)(cc >> 6) * N_TOK + row) * DHD + (cc & 63)] = f2bf(val);
          } else {
            comb[(size_t)row * COMBN + (col - 1536)] = f2bf(gelu_tanh(val));
          }
        } else {
          const size_t o = (size_t)row * HIDN + col;
          outp[o] = bf2f(xn[o]) + val;
        }
      }
    }
  }
}

// ------- pre-rotate Q (with 1/8 scale) and K, in place, bf16 -------
// block = 64 tokens; sin/cos staged once in LDS, applied to all 12 heads
__global__ __launch_bounds__(256) void rope_qk(
    unsigned short* __restrict__ qb, unsigned short* __restrict__ kb,
    const float* __restrict__ psin, const float* __restrict__ pcos)
{
  __shared__ float ss[2048], cc[2048];
  const int tid = threadIdx.x, g = blockIdx.x;
  #pragma unroll
  for (int rep = 0; rep < 8; rep++){
    int idx = rep * 256 + tid;
    int tok = idx >> 5, p = idx & 31;
    size_t gt = ((size_t)(g * 64 + tok)) * DHD + 2 * p;
    ss[idx] = psin[gt];
    cc[idx] = pcos[gt];
  }
  __syncthreads();
  unsigned* q32 = (unsigned*)qb;
  unsigned* k32 = (unsigned*)kb;
  for (int h = 0; h < NH; h++){
    #pragma unroll
    for (int rep = 0; rep < 8; rep++){
      int idx = rep * 256 + tid;
      int tok = idx >> 5, p = idx & 31;
      size_t a = ((size_t)h * N_TOK + g * 64 + tok) * 32 + p;
      float s = ss[tok * 32 + p], c0 = cc[tok * 32 + p];
      unsigned u = q32[a];
      float e = bf2f((unsigned short)(u & 0xffff));
      float d = bf2f((unsigned short)(u >> 16));
      q32[a] = (unsigned)f2bf((e * c0 - d * s) * 0.125f)
             | (((unsigned)f2bf((d * c0 + e * s) * 0.125f)) << 16);
      u = k32[a];
      e = bf2f((unsigned short)(u & 0xffff));
      d = bf2f((unsigned short)(u >> 16));
      k32[a] = (unsigned)f2bf(e * c0 - d * s)
             | (((unsigned)f2bf(d * c0 + e * s)) << 16);
    }
  }
}

// ------- chunked local attention: pre-roped Q/K, 64-key tiles -------
// block = (256-q chunk, head); 4 waves x 64 q; double-buffered K/V LDS,
// register prefetch, 1 barrier/tile; XOR-swizzled V^T; per-wave P scratch.
__global__ __launch_bounds__(256) void attn_kernel(
    const unsigned short* __restrict__ qb, const unsigned short* __restrict__ kb,
    const unsigned short* __restrict__ vb, unsigned short* __restrict__ comb,
    const int* __restrict__ lenp)
{
  __shared__ short Ks[2][64 * 72];   // [key][dh], pad 72 (conflict-free)
  __shared__ short Vt[2][64 * 64];   // [dh][key^], XOR-swizzled key blocks
  __shared__ short Ps[4][16 * 72];   // per-wave P scratch
  const int tid = threadIdx.x, lane = tid & 63, wv = tid >> 6;
  const int quad = lane >> 4, l15 = lane & 15;
  const int h = blockIdx.y, c = blockIdx.x;
  const unsigned lm = ~((unsigned)lenp[0] - 1u);
  const int i0 = c * CHUNK + wv * 64;
  const unsigned short* qh = qb + (size_t)h * N_TOK * DHD;
  const unsigned short* kh = kb + (size_t)h * N_TOK * DHD;
  const unsigned short* vh = vb + (size_t)h * N_TOK * DHD;

  // Q fragments (already roped+scaled): A-layout [m=l15][k=quad*8+j]
  s16x8 qf[4][2];
  #pragma unroll
  for (int rt = 0; rt < 4; rt++){
    const unsigned short* qr = qh + (size_t)(i0 + rt * 16 + l15) * DHD;
    qf[rt][0] = *(const s16x8*)(qr + quad * 8);
    qf[rt][1] = *(const s16x8*)(qr + 32 + quad * 8);
  }

  f32x4 O[4][4];
  float mm[4][4], ll[4][4];
  #pragma unroll
  for (int rt = 0; rt < 4; rt++)
    #pragma unroll
    for (int j = 0; j < 4; j++){ O[rt][j] = (f32x4){0,0,0,0}; mm[rt][j] = -1e30f; ll[rt][j] = 0.f; }
  short* myP = &Ps[wv][0];

  const int skey = tid & 63, sseg = tid >> 6;   // staging: key = tid&63 (sseg wave-uniform)
  const int jb0 = c * CHUNK - 256;
  s16x8 kr[2], vr[2];

  auto issue = [&](int jb){
    if (jb >= 0){
      const unsigned short* kp = kh + (size_t)(jb + skey) * DHD + sseg * 16;
      const unsigned short* vp = vh + (size_t)(jb + skey) * DHD + sseg * 16;
      kr[0] = *(const s16x8*)(kp);     kr[1] = *(const s16x8*)(kp + 8);
      vr[0] = *(const s16x8*)(vp);     vr[1] = *(const s16x8*)(vp + 8);
    } else {
      kr[0] = kr[1] = vr[0] = vr[1] = (s16x8){0,0,0,0,0,0,0,0};
    }
  };

  issue(jb0);
  for (int tb = 0; tb < 8; tb++){
    const int jb = jb0 + tb * 64;
    const int buf = tb & 1;
    short* Kb = &Ks[buf][0];
    short* Vb = &Vt[buf][0];
    // store staged regs
    *(s16x8*)(Kb + skey * 72 + sseg * 16)     = kr[0];
    *(s16x8*)(Kb + skey * 72 + sseg * 16 + 8) = kr[1];
    #pragma unroll
    for (int half = 0; half < 2; half++)
      #pragma unroll
      for (int j = 0; j < 8; j++){
        const int d = sseg * 16 + half * 8 + j;
        Vb[d * 64 + (((skey & 56) ^ ((d & 7) << 3)) | (skey & 7))] = vr[half][j];
      }
    if (tb < 7) issue(jb + 64);
    __syncthreads();

    const bool act = (jb >= 0) && (jb <= i0 + 63) && (jb + 63 >= i0 - 255) &&
                     (((unsigned)i0 & lm) == ((unsigned)jb & lm));
    if (!act) continue;

    #pragma unroll
    for (int rt = 0; rt < 4; rt++){
      const int ilo = i0 + rt * 16;
      if (ilo + 15 < jb || ilo - (jb + 63) >= WIN) continue;
      // QK^T: 4 ct x 2 kslices
      f32x4 sc[4];
      #pragma unroll
      for (int ct = 0; ct < 4; ct++){
        const short* kbase = Kb + (ct * 16 + l15) * 72 + quad * 8;
        const s16x8 b0 = *(const s16x8*)(kbase);
        const s16x8 b1 = *(const s16x8*)(kbase + 32);
        f32x4 a = (f32x4){0,0,0,0};
        a = __builtin_amdgcn_mfma_f32_16x16x32_bf16(qf[rt][0], b0, a, 0, 0, 0);
        a = __builtin_amdgcn_mfma_f32_16x16x32_bf16(qf[rt][1], b1, a, 0, 0, 0);
        sc[ct] = a;
      }
      float alph[4];
      #pragma unroll
      for (int r = 0; r < 4; r++){
        const int i = ilo + quad * 4 + r;
        #pragma unroll
        for (int ct = 0; ct < 4; ct++){
          const unsigned dd = (unsigned)(i - (jb + ct * 16 + l15));
          if (dd >= 256u) sc[ct][r] = -1e30f;
        }
        float mx = fmaxf(fmaxf(sc[0][r], sc[1][r]), fmaxf(sc[2][r], sc[3][r]));
        mx = fmaxf(mx, __shfl_xor(mx, 1));
        mx = fmaxf(mx, __shfl_xor(mx, 2));
        mx = fmaxf(mx, __shfl_xor(mx, 4));
        mx = fmaxf(mx, __shfl_xor(mx, 8));
        const float mnew = fmaxf(mm[rt][r], mx);
        alph[r] = __expf(mm[rt][r] - mnew);
        mm[rt][r] = mnew;
        float p0 = __expf(sc[0][r] - mnew);
        float p1 = __expf(sc[1][r] - mnew);
        float p2 = __expf(sc[2][r] - mnew);
        float p3 = __expf(sc[3][r] - mnew);
        sc[0][r] = p0; sc[1][r] = p1; sc[2][r] = p2; sc[3][r] = p3;
        float rsum = (p0 + p1) + (p2 + p3);
        rsum += __shfl_xor(rsum, 1);
        rsum += __shfl_xor(rsum, 2);
        rsum += __shfl_xor(rsum, 4);
        rsum += __shfl_xor(rsum, 8);
        ll[rt][r] = ll[rt][r] * alph[r] + rsum;
      }
      #pragma unroll
      for (int co = 0; co < 4; co++)
        #pragma unroll
        for (int r = 0; r < 4; r++) O[rt][co][r] *= alph[r];
      // P -> per-wave LDS scratch (A-layout read-back)
      #pragma unroll
      for (int r = 0; r < 4; r++){
        const int prow = quad * 4 + r;
        #pragma unroll
        for (int ct = 0; ct < 4; ct++)
          myP[prow * 72 + ct * 16 + l15] = (short)f2bf(sc[ct][r]);
      }
      #pragma unroll
      for (int ks2 = 0; ks2 < 2; ks2++){
        const s16x8 pf = *(const s16x8*)(myP + l15 * 72 + ks2 * 32 + quad * 8);
        #pragma unroll
        for (int co = 0; co < 4; co++){
          const int d = co * 16 + l15;
          const s16x8 vf = *(const s16x8*)(Vb + d * 64 +
                              ((ks2 * 32 + quad * 8) ^ ((d & 7) << 3)));
          O[rt][co] = __builtin_amdgcn_mfma_f32_16x16x32_bf16(pf, vf, O[rt][co], 0, 0, 0);
        }
      }
    }
  }

  #pragma unroll
  for (int rt = 0; rt < 4; rt++)
    #pragma unroll
    for (int co = 0; co < 4; co++)
      #pragma unroll
      for (int r = 0; r < 4; r++){
        const int tok = i0 + rt * 16 + quad * 4 + r;
        comb[(size_t)tok * COMBN + h * DHD + co * 16 + l15] = f2bf(O[rt][co][r] / ll[rt][r]);
      }
}

extern "C" void kernel_launch(void* const* d_in, const int* in_sizes, int n_in,
                              void* d_out, int out_size, void* d_ws, size_t ws_size,
                              hipStream_t stream)
{
  const float* x     = (const float*)d_in[0];
  const float* psin  = (const float*)d_in[2];
  const float* pcos  = (const float*)d_in[3];
  const float* lns   = (const float*)d_in[4];
  const float* lno   = (const float*)d_in[5];
  const float* w_in  = (const float*)d_in[6];
  const float* b_in  = (const float*)d_in[7];
  const float* w_out = (const float*)d_in[8];
  const float* b_out = (const float*)d_in[9];
  const int*   lenp  = (const int*)d_in[10];
  float* out = (float*)d_out;

  char* ws = (char*)d_ws;
  size_t off = 0;
  unsigned short* xn    = (unsigned short*)(ws + off); off += (size_t)N_TOK * HIDN * 2;
  unsigned short* wInT  = (unsigned short*)(ws + off); off += (size_t)MIDN * HIDN * 2;
  unsigned short* wOutT = (unsigned short*)(ws + off); off += (size_t)HIDN * COMBN * 2;
  unsigned short* qbuf  = (unsigned short*)(ws + off); off += (size_t)NH * N_TOK * DHD * 2;
  unsigned short* kbuf  = (unsigned short*)(ws + off); off += (size_t)NH * N_TOK * DHD * 2;
  unsigned short* vbuf  = (unsigned short*)(ws + off); off += (size_t)NH * N_TOK * DHD * 2;
  unsigned short* comb  = (unsigned short*)(ws + off); off += (size_t)N_TOK * COMBN * 2;

  transpose_f2b<<<dim3(MIDN/64, HIDN/64), 256, 0, stream>>>(w_in, wInT, HIDN, MIDN);
  transpose_f2b<<<dim3(HIDN/64, COMBN/64), 256, 0, stream>>>(w_out, wOutT, COMBN, HIDN);
  ln_kernel<<<dim3(N_TOK/4), 256, 0, stream>>>(x, lns, lno, xn);
  gemm_bt<<<dim3(MIDN/128, N_TOK/128), 256, 0, stream>>>(
      xn, wInT, b_in, HIDN, 0, qbuf, kbuf, vbuf, comb, nullptr, nullptr);
  rope_qk<<<dim3(N_TOK/64), 256, 0, stream>>>(qbuf, kbuf, psin, pcos);
  attn_kernel<<<dim3(N_TOK/CHUNK, NH), 256, 0, stream>>>(
      qbuf, kbuf, vbuf, comb, lenp);
  gemm_bt<<<dim3(HIDN/128, N_TOK/128), 256, 0, stream>>>(
      comb, wOutT, b_out, COMBN, 1, nullptr, nullptr, nullptr, nullptr, xn, out);
}

// Round 4
// 692.556 us; speedup vs baseline: 1.1721x; 1.0450x over previous
//
#include <hip/hip_runtime.h>

#define N_TOK 16384
#define HIDN  768
#define MIDN  5376
#define COMBN 3840
#define NH    12
#define DHD   64
#define CHUNK 256
#define WIN   256

typedef short s16x8 __attribute__((ext_vector_type(8)));
typedef short s16x4 __attribute__((ext_vector_type(4)));
typedef float f32x4 __attribute__((ext_vector_type(4)));

__device__ __forceinline__ float bf2f(unsigned short u){
  union { unsigned u; float f; } x; x.u = ((unsigned)u) << 16; return x.f;
}
__device__ __forceinline__ unsigned short f2bf(float f){
  union { float f; unsigned u; } x; x.f = f;
  unsigned r = x.u + 0x7fffu + ((x.u >> 16) & 1u);
  return (unsigned short)(r >> 16);
}
__device__ __forceinline__ float gelu_fast(float x){
  // 0.5x(1+tanh(0.79788456(x+0.044715x^3))) == x / (1 + exp(-2*0.79788456*(...)))
  float u = -1.5957691216057308f * (x + 0.044715f * x * x * x);
  return x / (1.f + __expf(u));
}
__device__ __forceinline__ void glds16(const void* g, void* l){
  __builtin_amdgcn_global_load_lds(
      (const __attribute__((address_space(1))) unsigned*)g,
      (__attribute__((address_space(3))) unsigned*)l, 16, 0, 0);
}

// ------- transpose + downcast: in fp32 [R][Cc] -> out bf16 [Cc][R] -------
__global__ __launch_bounds__(256) void transpose_f2b(
    const float* __restrict__ in, unsigned short* __restrict__ out,
    int R, int Cc)
{
  __shared__ short t[64 * 72];
  const int tid = threadIdx.x;
  const int r0 = blockIdx.y * 64, c0 = blockIdx.x * 64;
  #pragma unroll
  for (int rep = 0; rep < 4; rep++){
    int v = tid + 256 * rep;
    int r = v >> 4, s = v & 15;
    float4 d = *(const float4*)(in + (size_t)(r0 + r) * Cc + c0 + s * 4);
    s16x4 o = { (short)f2bf(d.x), (short)f2bf(d.y), (short)f2bf(d.z), (short)f2bf(d.w) };
    *(s16x4*)(t + r * 72 + s * 4) = o;
  }
  __syncthreads();
  #pragma unroll
  for (int rep = 0; rep < 2; rep++){
    int v = tid + 256 * rep;
    int c = v & 63, s2 = v >> 6;
    s16x8 d;
    #pragma unroll
    for (int j = 0; j < 8; j++) d[j] = t[(s2 * 8 + j) * 72 + c];
    *(s16x8*)(out + (size_t)(c0 + c) * R + r0 + s2 * 8) = d;
  }
}

// ------- layernorm: fp32 in -> bf16 out, one wave per row -------
__global__ __launch_bounds__(256) void ln_kernel(
    const float* __restrict__ x, const float* __restrict__ sc,
    const float* __restrict__ ofs, unsigned short* __restrict__ xn)
{
  const int lane = threadIdx.x & 63, wv = threadIdx.x >> 6;
  const int row = blockIdx.x * 4 + wv;
  const float4* xr = (const float4*)(x + (size_t)row * HIDN);
  float4 vals[3];
  float sum = 0.f, sq = 0.f;
  #pragma unroll
  for (int j = 0; j < 3; j++){
    vals[j] = xr[lane + 64 * j];
    sum += vals[j].x + vals[j].y + vals[j].z + vals[j].w;
    sq  += vals[j].x * vals[j].x + vals[j].y * vals[j].y
         + vals[j].z * vals[j].z + vals[j].w * vals[j].w;
  }
  #pragma unroll
  for (int o = 1; o < 64; o <<= 1){ sum += __shfl_xor(sum, o); sq += __shfl_xor(sq, o); }
  const float mu = sum * (1.f / HIDN);
  const float rs = rsqrtf(fmaxf(sq * (1.f / HIDN) - mu * mu, 0.f) + 1e-5f);
  s16x4* xo = (s16x4*)(xn + (size_t)row * HIDN);
  const float4* scp = (const float4*)sc;
  const float4* ofp = (const float4*)ofs;
  #pragma unroll
  for (int j = 0; j < 3; j++){
    int p = lane + 64 * j;
    float4 s = scp[p], o = ofp[p];
    s16x4 w;
    w[0] = (short)f2bf((vals[j].x - mu) * rs * s.x + o.x);
    w[1] = (short)f2bf((vals[j].y - mu) * rs * s.y + o.y);
    w[2] = (short)f2bf((vals[j].z - mu) * rs * s.z + o.z);
    w[3] = (short)f2bf((vals[j].w - mu) * rs * s.w + o.w);
    xo[p] = w;
  }
}

// LDS swizzle: chunk c of a (rows x 32) bf16 tile holds row=c>>2,
// seg=(c&3)^((c>>3)&3). Read offset for (row, quad): row*64 + ((quad^((row>>1)&3))<<4)
// -> exactly 2 lanes/bank on b128 fragment reads (free), glds16-compatible.
__device__ __forceinline__ int swz(int row, int quad){
  return row * 64 + ((quad ^ ((row >> 1) & 3)) << 4);
}

// ------- GEMM1: [16384x768] x [5376x768]^T, 256x128 tile, acc 4x8/wave -------
__global__ __launch_bounds__(256, 2) void gemm1_k(
    const unsigned short* __restrict__ A, const unsigned short* __restrict__ BT,
    const float* __restrict__ bias,
    unsigned short* __restrict__ qb, unsigned short* __restrict__ kb,
    unsigned short* __restrict__ vb, unsigned short* __restrict__ comb)
{
  constexpr int K = HIDN;
  __shared__ short As[256 * 32];
  __shared__ short Bs[128 * 32];
  const int tid = threadIdx.x, lane = tid & 63, wv = tid >> 6;
  const int quad = lane >> 4, l15 = lane & 15;
  const int n0 = blockIdx.x * 128, m0 = blockIdx.y * 256;

  f32x4 acc[4][8];
  #pragma unroll
  for (int i = 0; i < 4; i++)
    #pragma unroll
    for (int j = 0; j < 8; j++) acc[i][j] = (f32x4){0.f,0.f,0.f,0.f};

  const int srow = tid >> 2;
  const int sseg = (tid & 3) ^ ((tid >> 3) & 3);
  const unsigned short* Ap = A  + (size_t)(m0 + srow) * K + sseg * 8;
  const unsigned short* Bp = BT + (size_t)(n0 + srow) * K + sseg * 8;
  const size_t rstep = (size_t)64 * K;
  char* AsB = ((char*)As) + tid * 16;
  char* BsB = ((char*)Bs) + tid * 16;

  int offA[4], offB[8];
  #pragma unroll
  for (int rt = 0; rt < 4; rt++) offA[rt] = swz(wv * 64 + rt * 16 + l15, quad);
  #pragma unroll
  for (int ct = 0; ct < 8; ct++) offB[ct] = swz(ct * 16 + l15, quad);

  for (int kt = 0; kt < K; kt += 32){
    __syncthreads();
    glds16(Ap + kt,             AsB);
    glds16(Ap + kt + rstep,     AsB + 4096);
    glds16(Ap + kt + 2 * rstep, AsB + 8192);
    glds16(Ap + kt + 3 * rstep, AsB + 12288);
    glds16(Bp + kt,             BsB);
    glds16(Bp + kt + rstep,     BsB + 4096);
    __syncthreads();
    s16x8 a[4], b[8];
    #pragma unroll
    for (int rt = 0; rt < 4; rt++) a[rt] = *(const s16x8*)((const char*)As + offA[rt]);
    #pragma unroll
    for (int ct = 0; ct < 8; ct++) b[ct] = *(const s16x8*)((const char*)Bs + offB[ct]);
    #pragma unroll
    for (int rt = 0; rt < 4; rt++)
      #pragma unroll
      for (int ct = 0; ct < 8; ct++)
        acc[rt][ct] = __builtin_amdgcn_mfma_f32_16x16x32_bf16(a[rt], b[ct], acc[rt][ct], 0, 0, 0);
  }

  // block-uniform output class (boundaries 768/1536/2304 are multiples of 128)
  unsigned short* dstb; int cb; bool isff = false;
  if (n0 < 768)       { dstb = qb;   cb = n0; }
  else if (n0 < 1536) { dstb = kb;   cb = n0 - 768; }
  else if (n0 < 2304) { dstb = vb;   cb = n0 - 1536; }
  else                { dstb = comb; cb = n0 - 1536; isff = true; }
  const int rowstride = isff ? COMBN : HIDN;

  #pragma unroll
  for (int ct = 0; ct < 8; ct++){
    const float bsv = bias[n0 + ct * 16 + l15];
    const int col = cb + ct * 16 + l15;
    #pragma unroll
    for (int rt = 0; rt < 4; rt++){
      #pragma unroll
      for (int r = 0; r < 4; r++){
        const int row = m0 + wv * 64 + rt * 16 + quad * 4 + r;
        float val = acc[rt][ct][r] + bsv;
        if (isff) val = gelu_fast(val);
        dstb[(size_t)row * rowstride + col] = f2bf(val);
      }
    }
  }
}

// ------- GEMM2: [16384x3840] x [768x3840]^T + b + xn residual -> fp32 out -------
__global__ __launch_bounds__(256) void gemm2_k(
    const unsigned short* __restrict__ A, const unsigned short* __restrict__ BT,
    const float* __restrict__ bias, const unsigned short* __restrict__ xn,
    float* __restrict__ outp)
{
  constexpr int K = COMBN;
  __shared__ short As[128 * 32];
  __shared__ short Bs[128 * 32];
  const int tid = threadIdx.x, lane = tid & 63, wv = tid >> 6;
  const int quad = lane >> 4, l15 = lane & 15;
  const int m0 = blockIdx.y * 128, n0 = blockIdx.x * 128;
  const int wr = (wv >> 1) * 64, wc = (wv & 1) * 64;

  f32x4 acc[4][4];
  #pragma unroll
  for (int i = 0; i < 4; i++)
    #pragma unroll
    for (int j = 0; j < 4; j++) acc[i][j] = (f32x4){0.f,0.f,0.f,0.f};

  const int srow = tid >> 2;
  const int sseg = (tid & 3) ^ ((tid >> 3) & 3);
  const unsigned short* Ap = A  + (size_t)(m0 + srow) * K + sseg * 8;
  const unsigned short* Bp = BT + (size_t)(n0 + srow) * K + sseg * 8;
  const size_t rstep = (size_t)64 * K;
  char* AsB = ((char*)As) + tid * 16;
  char* BsB = ((char*)Bs) + tid * 16;

  int offA[4], offB[4];
  #pragma unroll
  for (int rt = 0; rt < 4; rt++) offA[rt] = swz(wr + rt * 16 + l15, quad);
  #pragma unroll
  for (int ct = 0; ct < 4; ct++) offB[ct] = swz(wc + ct * 16 + l15, quad);

  for (int kt = 0; kt < K; kt += 32){
    __syncthreads();
    glds16(Ap + kt,         AsB);
    glds16(Ap + kt + rstep, AsB + 4096);
    glds16(Bp + kt,         BsB);
    glds16(Bp + kt + rstep, BsB + 4096);
    __syncthreads();
    s16x8 a[4], b[4];
    #pragma unroll
    for (int rt = 0; rt < 4; rt++) a[rt] = *(const s16x8*)((const char*)As + offA[rt]);
    #pragma unroll
    for (int ct = 0; ct < 4; ct++) b[ct] = *(const s16x8*)((const char*)Bs + offB[ct]);
    #pragma unroll
    for (int rt = 0; rt < 4; rt++)
      #pragma unroll
      for (int ct = 0; ct < 4; ct++)
        acc[rt][ct] = __builtin_amdgcn_mfma_f32_16x16x32_bf16(a[rt], b[ct], acc[rt][ct], 0, 0, 0);
  }

  #pragma unroll
  for (int ct = 0; ct < 4; ct++){
    const int col = n0 + wc + ct * 16 + l15;
    const float bsv = bias[col];
    #pragma unroll
    for (int rt = 0; rt < 4; rt++){
      #pragma unroll
      for (int r = 0; r < 4; r++){
        const int row = m0 + wr + rt * 16 + quad * 4 + r;
        const size_t o = (size_t)row * HIDN + col;
        outp[o] = bf2f(xn[o]) + acc[rt][ct][r] + bsv;
      }
    }
  }
}

// ------- pre-rotate Q (with 1/8 scale) and K in place; layout [tok][768] -------
__global__ __launch_bounds__(384) void rope_qk(
    unsigned short* __restrict__ qb, unsigned short* __restrict__ kb,
    const float* __restrict__ psin, const float* __restrict__ pcos)
{
  __shared__ float ss[2048], cs[2048];
  const int tid = threadIdx.x, g = blockIdx.x;
  #pragma unroll
  for (int rep = 0; rep < 6; rep++){
    int idx = rep * 384 + tid;
    if (idx < 2048){
      int tok = idx >> 5, p = idx & 31;
      size_t gt = ((size_t)(g * 64 + tok)) * DHD + 2 * p;
      ss[idx] = psin[gt];
      cs[idx] = pcos[gt];
    }
  }
  __syncthreads();
  const int p = tid & 31;
  unsigned* q32 = (unsigned*)qb;
  unsigned* k32 = (unsigned*)kb;
  for (int tok = 0; tok < 64; tok++){
    const size_t a = ((size_t)(g * 64 + tok)) * 384 + tid;
    const float s = ss[tok * 32 + p], c0 = cs[tok * 32 + p];
    unsigned u = q32[a];
    float e = bf2f((unsigned short)(u & 0xffff));
    float d = bf2f((unsigned short)(u >> 16));
    q32[a] = (unsigned)f2bf((e * c0 - d * s) * 0.125f)
           | (((unsigned)f2bf((d * c0 + e * s) * 0.125f)) << 16);
    u = k32[a];
    e = bf2f((unsigned short)(u & 0xffff));
    d = bf2f((unsigned short)(u >> 16));
    k32[a] = (unsigned)f2bf(e * c0 - d * s)
           | (((unsigned)f2bf(d * c0 + e * s)) << 16);
  }
}

// ------- chunked local attention: pre-roped Q/K [tok][768], 64-key tiles -------
__global__ __launch_bounds__(256) void attn_kernel(
    const unsigned short* __restrict__ qb, const unsigned short* __restrict__ kb,
    const unsigned short* __restrict__ vb, unsigned short* __restrict__ comb,
    const int* __restrict__ lenp)
{
  __shared__ short Ks[2][64 * 72];
  __shared__ short Vt[2][64 * 64];
  __shared__ short Ps[4][16 * 72];
  const int tid = threadIdx.x, lane = tid & 63, wv = tid >> 6;
  const int quad = lane >> 4, l15 = lane & 15;
  const int h = blockIdx.y, c = blockIdx.x;
  const unsigned lm = ~((unsigned)lenp[0] - 1u);
  const int i0 = c * CHUNK + wv * 64;
  const unsigned short* qh = qb + h * DHD;
  const unsigned short* kh = kb + h * DHD;
  const unsigned short* vh = vb + h * DHD;

  s16x8 qf[4][2];
  #pragma unroll
  for (int rt = 0; rt < 4; rt++){
    const unsigned short* qr = qh + (size_t)(i0 + rt * 16 + l15) * HIDN;
    qf[rt][0] = *(const s16x8*)(qr + quad * 8);
    qf[rt][1] = *(const s16x8*)(qr + 32 + quad * 8);
  }

  f32x4 O[4][4];
  float mm[4][4], ll[4][4];
  #pragma unroll
  for (int rt = 0; rt < 4; rt++)
    #pragma unroll
    for (int j = 0; j < 4; j++){ O[rt][j] = (f32x4){0,0,0,0}; mm[rt][j] = -1e30f; ll[rt][j] = 0.f; }
  short* myP = &Ps[wv][0];

  const int skey = tid & 63, sseg = tid >> 6;
  const int jb0 = c * CHUNK - 256;
  s16x8 kr[2], vr[2];

  auto issue = [&](int jb){
    if (jb >= 0){
      const unsigned short* kp = kh + (size_t)(jb + skey) * HIDN + sseg * 16;
      const unsigned short* vp = vh + (size_t)(jb + skey) * HIDN + sseg * 16;
      kr[0] = *(const s16x8*)(kp);     kr[1] = *(const s16x8*)(kp + 8);
      vr[0] = *(const s16x8*)(vp);     vr[1] = *(const s16x8*)(vp + 8);
    } else {
      kr[0] = kr[1] = vr[0] = vr[1] = (s16x8){0,0,0,0,0,0,0,0};
    }
  };

  issue(jb0);
  for (int tb = 0; tb < 8; tb++){
    const int jb = jb0 + tb * 64;
    const int buf = tb & 1;
    short* Kb = &Ks[buf][0];
    short* Vb = &Vt[buf][0];
    *(s16x8*)(Kb + skey * 72 + sseg * 16)     = kr[0];
    *(s16x8*)(Kb + skey * 72 + sseg * 16 + 8) = kr[1];
    #pragma unroll
    for (int half = 0; half < 2; half++)
      #pragma unroll
      for (int j = 0; j < 8; j++){
        const int d = sseg * 16 + half * 8 + j;
        Vb[d * 64 + (((skey & 56) ^ ((d & 7) << 3)) | (skey & 7))] = vr[half][j];
      }
    if (tb < 7) issue(jb + 64);
    __syncthreads();

    const bool act = (jb >= 0) && (jb <= i0 + 63) && (jb + 63 >= i0 - 255) &&
                     (((unsigned)i0 & lm) == ((unsigned)jb & lm));
    if (!act) continue;

    #pragma unroll
    for (int rt = 0; rt < 4; rt++){
      const int ilo = i0 + rt * 16;
      if (ilo + 15 < jb || ilo - (jb + 63) >= WIN) continue;
      f32x4 sc[4];
      #pragma unroll
      for (int ct = 0; ct < 4; ct++){
        const short* kbase = Kb + (ct * 16 + l15) * 72 + quad * 8;
        const s16x8 b0 = *(const s16x8*)(kbase);
        const s16x8 b1 = *(const s16x8*)(kbase + 32);
        f32x4 a = (f32x4){0,0,0,0};
        a = __builtin_amdgcn_mfma_f32_16x16x32_bf16(qf[rt][0], b0, a, 0, 0, 0);
        a = __builtin_amdgcn_mfma_f32_16x16x32_bf16(qf[rt][1], b1, a, 0, 0, 0);
        sc[ct] = a;
      }
      float alph[4];
      #pragma unroll
      for (int r = 0; r < 4; r++){
        const int i = ilo + quad * 4 + r;
        #pragma unroll
        for (int ct = 0; ct < 4; ct++){
          const unsigned dd = (unsigned)(i - (jb + ct * 16 + l15));
          if (dd >= 256u) sc[ct][r] = -1e30f;
        }
        float mx = fmaxf(fmaxf(sc[0][r], sc[1][r]), fmaxf(sc[2][r], sc[3][r]));
        mx = fmaxf(mx, __shfl_xor(mx, 1));
        mx = fmaxf(mx, __shfl_xor(mx, 2));
        mx = fmaxf(mx, __shfl_xor(mx, 4));
        mx = fmaxf(mx, __shfl_xor(mx, 8));
        const float mnew = fmaxf(mm[rt][r], mx);
        alph[r] = __expf(mm[rt][r] - mnew);
        mm[rt][r] = mnew;
        float p0 = __expf(sc[0][r] - mnew);
        float p1 = __expf(sc[1][r] - mnew);
        float p2 = __expf(sc[2][r] - mnew);
        float p3 = __expf(sc[3][r] - mnew);
        sc[0][r] = p0; sc[1][r] = p1; sc[2][r] = p2; sc[3][r] = p3;
        float rsum = (p0 + p1) + (p2 + p3);
        rsum += __shfl_xor(rsum, 1);
        rsum += __shfl_xor(rsum, 2);
        rsum += __shfl_xor(rsum, 4);
        rsum += __shfl_xor(rsum, 8);
        ll[rt][r] = ll[rt][r] * alph[r] + rsum;
      }
      #pragma unroll
      for (int co = 0; co < 4; co++)
        #pragma unroll
        for (int r = 0; r < 4; r++) O[rt][co][r] *= alph[r];
      #pragma unroll
      for (int r = 0; r < 4; r++){
        const int prow = quad * 4 + r;
        #pragma unroll
        for (int ct = 0; ct < 4; ct++)
          myP[prow * 72 + ct * 16 + l15] = (short)f2bf(sc[ct][r]);
      }
      #pragma unroll
      for (int ks2 = 0; ks2 < 2; ks2++){
        const s16x8 pf = *(const s16x8*)(myP + l15 * 72 + ks2 * 32 + quad * 8);
        #pragma unroll
        for (int co = 0; co < 4; co++){
          const int d = co * 16 + l15;
          const s16x8 vf = *(const s16x8*)(Vb + d * 64 +
                              ((ks2 * 32 + quad * 8) ^ ((d & 7) << 3)));
          O[rt][co] = __builtin_amdgcn_mfma_f32_16x16x32_bf16(pf, vf, O[rt][co], 0, 0, 0);
        }
      }
    }
  }

  #pragma unroll
  for (int rt = 0; rt < 4; rt++)
    #pragma unroll
    for (int co = 0; co < 4; co++)
      #pragma unroll
      for (int r = 0; r < 4; r++){
        const int tok = i0 + rt * 16 + quad * 4 + r;
        comb[(size_t)tok * COMBN + h * DHD + co * 16 + l15] = f2bf(O[rt][co][r] / ll[rt][r]);
      }
}

extern "C" void kernel_launch(void* const* d_in, const int* in_sizes, int n_in,
                              void* d_out, int out_size, void* d_ws, size_t ws_size,
                              hipStream_t stream)
{
  const float* x     = (const float*)d_in[0];
  const float* psin  = (const float*)d_in[2];
  const float* pcos  = (const float*)d_in[3];
  const float* lns   = (const float*)d_in[4];
  const float* lno   = (const float*)d_in[5];
  const float* w_in  = (const float*)d_in[6];
  const float* b_in  = (const float*)d_in[7];
  const float* w_out = (const float*)d_in[8];
  const float* b_out = (const float*)d_in[9];
  const int*   lenp  = (const int*)d_in[10];
  float* out = (float*)d_out;

  char* ws = (char*)d_ws;
  size_t off = 0;
  unsigned short* xn    = (unsigned short*)(ws + off); off += (size_t)N_TOK * HIDN * 2;
  unsigned short* wInT  = (unsigned short*)(ws + off); off += (size_t)MIDN * HIDN * 2;
  unsigned short* wOutT = (unsigned short*)(ws + off); off += (size_t)HIDN * COMBN * 2;
  unsigned short* qbuf  = (unsigned short*)(ws + off); off += (size_t)N_TOK * HIDN * 2;
  unsigned short* kbuf  = (unsigned short*)(ws + off); off += (size_t)N_TOK * HIDN * 2;
  unsigned short* vbuf  = (unsigned short*)(ws + off); off += (size_t)N_TOK * HIDN * 2;
  unsigned short* comb  = (unsigned short*)(ws + off); off += (size_t)N_TOK * COMBN * 2;

  transpose_f2b<<<dim3(MIDN/64, HIDN/64), 256, 0, stream>>>(w_in, wInT, HIDN, MIDN);
  transpose_f2b<<<dim3(HIDN/64, COMBN/64), 256, 0, stream>>>(w_out, wOutT, COMBN, HIDN);
  ln_kernel<<<dim3(N_TOK/4), 256, 0, stream>>>(x, lns, lno, xn);
  gemm1_k<<<dim3(MIDN/128, N_TOK/256), 256, 0, stream>>>(
      xn, wInT, b_in, qbuf, kbuf, vbuf, comb);
  rope_qk<<<dim3(N_TOK/64), 384, 0, stream>>>(qbuf, kbuf, psin, pcos);
  attn_kernel<<<dim3(N_TOK/CHUNK, NH), 256, 0, stream>>>(
      qbuf, kbuf, vbuf, comb, lenp);
  gemm2_k<<<dim3(HIDN/128, N_TOK/128), 256, 0, stream>>>(
      comb, wOutT, b_out, xn, out);
}